// Round 19
// baseline (154.422 us; speedup 1.0000x reference)
//
#include <hip/hip_runtime.h>

#define N_NODES 8192
#define D_IN 512
#define D_OUT 64
#define LRELU_ALPHA 0.2f
#define KSPLIT 8
#define KSLICE (N_NODES / KSPLIT)    // 1024 cols per attn block
#define NCHUNK (KSLICE / 64)         // 16 windows of 64 cols
#define NSTEP (NCHUNK / 2)           // 8 stage-steps (2 windows each)
#define GEMM_BLOCKS (N_NODES / 32)   // 256

typedef __attribute__((ext_vector_type(8))) short bf16x8;
typedef __attribute__((ext_vector_type(4))) float f32x4;

__device__ __forceinline__ unsigned short f2bf(float x) {
    unsigned u = __float_as_uint(x);
    u += 0x7fffu + ((u >> 16) & 1u);   // round-to-nearest-even
    return (unsigned short)(u >> 16);
}

// bit-gated p: e = lrelu(wh1+w2); p = bit ? exp(e) : 0
__device__ __forceinline__ float pb(unsigned bits, int pos, float w2v, float wh1v, float& lsum) {
    float e = wh1v + w2v;
    e = fmaxf(e, LRELU_ALPHA * e);
    float p = ((bits >> pos) & 1u) ? __expf(e) : 0.f;
    lsum += p;
    return p;
}

// ---------------- Kernel A (fused front): gemm blocks [0,256) + maskbits blocks [256,2304) ----------------
// (byte-identical to R18's passing version)
__global__ __launch_bounds__(256) void k_front(const float* __restrict__ h,
                                               const float* __restrict__ W,
                                               const float* __restrict__ a,
                                               const float* __restrict__ mask,
                                               unsigned short* __restrict__ WhTp3,
                                               float* __restrict__ Wh1,
                                               float* __restrict__ Wh2,
                                               unsigned long long* __restrict__ bits) {
    __shared__ float hs[32][68];
    __shared__ float Ws[64][64];

    if (blockIdx.x >= GEMM_BLOCKS) {
        const int bid = blockIdx.x - GEMM_BLOCKS;
        const int wave = threadIdx.x >> 6;
        const int lane = threadIdx.x & 63;
        const int row = bid * 4 + wave;
        const float4* m4 = (const float4*)(mask + (size_t)row * N_NODES);
        const int strip = row >> 4;
        const int r16 = row & 15;
        #pragma unroll 4
        for (int q = 0; q < 32; ++q) {
            const float4 v = m4[q * 64 + lane];
            const unsigned long long b0 = __ballot(v.x > 0.f);
            const unsigned long long b1 = __ballot(v.y > 0.f);
            const unsigned long long b2 = __ballot(v.z > 0.f);
            const unsigned long long b3 = __ballot(v.w > 0.f);
            if (lane == 0) {
                unsigned long long* dst = bits + (((size_t)strip * 32 + q) * 16 + r16) * 4;
                ulonglong2 t0; t0.x = b0; t0.y = b1;
                ulonglong2 t1; t1.x = b2; t1.y = b3;
                *(ulonglong2*)(dst)     = t0;
                *(ulonglong2*)(dst + 2) = t1;
            }
        }
        return;
    }

    const int tid = threadIdx.x;
    const int r0 = blockIdx.x * 32;
    const int tf = tid & 15;
    const int tr = tid >> 4;
    float acc[2][4] = {{0.f,0.f,0.f,0.f},{0.f,0.f,0.f,0.f}};

    for (int kc = 0; kc < D_IN; kc += 64) {
        {
            int rr = tid >> 4;
            int cc = (tid & 15) * 4;
            float4 v0 = *(const float4*)&h[(size_t)(r0 + rr) * D_IN + kc + cc];
            float4 v1 = *(const float4*)&h[(size_t)(r0 + rr + 16) * D_IN + kc + cc];
            *(float4*)&hs[rr][cc] = v0;
            *(float4*)&hs[rr + 16][cc] = v1;
        }
        #pragma unroll
        for (int p = 0; p < 4; ++p) {
            int kk = (tid >> 4) + p * 16;
            int cc = (tid & 15) * 4;
            *(float4*)&Ws[kk][cc] = *(const float4*)&W[(size_t)(kc + kk) * D_OUT + cc];
        }
        __syncthreads();
        #pragma unroll
        for (int k = 0; k < 64; k += 4) {
            float4 a0 = *(const float4*)&hs[tr*2][k];
            float4 a1 = *(const float4*)&hs[tr*2+1][k];
            float av0[4] = {a0.x, a0.y, a0.z, a0.w};
            float av1[4] = {a1.x, a1.y, a1.z, a1.w};
            #pragma unroll
            for (int kk = 0; kk < 4; ++kk) {
                float4 b = *(const float4*)&Ws[k+kk][tf*4];
                acc[0][0] += av0[kk]*b.x; acc[0][1] += av0[kk]*b.y;
                acc[0][2] += av0[kk]*b.z; acc[0][3] += av0[kk]*b.w;
                acc[1][0] += av1[kk]*b.x; acc[1][1] += av1[kk]*b.y;
                acc[1][2] += av1[kk]*b.z; acc[1][3] += av1[kk]*b.w;
            }
        }
        __syncthreads();
    }
    const int orow = r0 + tr*2;   // even

    {
        const int cc  = orow >> 6;
        const int cw  = orow & 63;
        const int hh  = cw >> 5;
        const int rem = cw & 31;
        const int jhi = rem >> 4;
        const int gg  = (rem >> 2) & 3;
        const int jlo = cw & 3;          // even
        const int j   = jhi * 4 + jlo;
        #pragma unroll
        for (int k = 0; k < 4; ++k) {
            const int f = tf * 4 + k;
            const int L = gg * 16 + (f & 15);
            const int s = (2 * (f >> 4) + hh) ^ (L & 7);
            const size_t sidx = ((size_t)(cc * 64 + L) * 8 + s) * 8 + j;
            unsigned v = (unsigned)f2bf(acc[0][k]) | ((unsigned)f2bf(acc[1][k]) << 16);
            *(unsigned*)&WhTp3[sidx] = v;
        }
    }

    float a1v[4], a2v[4];
    #pragma unroll
    for (int k = 0; k < 4; ++k) { a1v[k] = a[tf*4 + k]; a2v[k] = a[64 + tf*4 + k]; }
    float s1 = 0.f, t1 = 0.f, s2 = 0.f, t2 = 0.f;
    #pragma unroll
    for (int k = 0; k < 4; ++k) {
        s1 += acc[0][k] * a1v[k];
        t1 += acc[1][k] * a1v[k];
        s2 += acc[0][k] * a2v[k];
        t2 += acc[1][k] * a2v[k];
    }
    #pragma unroll
    for (int d = 1; d < 16; d <<= 1) {
        s1 += __shfl_xor(s1, d);
        t1 += __shfl_xor(t1, d);
        s2 += __shfl_xor(s2, d);
        t2 += __shfl_xor(t2, d);
    }
    if (tf == 0) {
        Wh1[orow] = s1; Wh1[orow + 1] = t1;
        Wh2[orow] = s2; Wh2[orow + 1] = t2;
    }
}

// ---------------- Kernel B: bit-gated masked-softmax + PV, 2-window steps, DMA-youngest ----------------
// R18 + three fixes: (1) reg loads (bits + both Wh2 windows) issued BEFORE the staging
// DMAs, so compute's compiler waits leave the DMA in flight (R9 in-order-retire lesson);
// (2) 2 windows per barrier (8 drains instead of 16), sharing ONE bits load (both windows
// of a step have the same q); (3) LDS 32KB at (512,4) -> 4 blocks/CU = 32 waves/CU.
__global__ __launch_bounds__(512, 4) void k_attn(const unsigned long long* __restrict__ bits,
                                                 const unsigned short* __restrict__ WhTp3,
                                                 const float* __restrict__ Wh1,
                                                 const float* __restrict__ Wh2,
                                                 float* __restrict__ pacc,
                                                 float* __restrict__ plsum) {
    __shared__ unsigned short bbuf[2][2][4096];   // [par][window][8KB]

    const int tid  = threadIdx.x;
    const int wave = tid >> 6;       // 0..7: strip within rowgroup
    const int lane = tid & 63;
    const int i16 = lane & 15;
    const int g   = lane >> 4;
    const int rg    = blockIdx.x >> 3;
    const int slice = blockIdx.x & 7;
    const int Rw    = rg * 128 + wave * 16;
    const int strip = rg * 8 + wave;
    const int ccbase = slice * NCHUNK;

    const float wh1v = Wh1[Rw + i16];

    f32x4 acc0 = {0.f,0.f,0.f,0.f}, acc1 = {0.f,0.f,0.f,0.f};
    f32x4 acc2 = {0.f,0.f,0.f,0.f}, acc3 = {0.f,0.f,0.f,0.f};
    float lsum = 0.f;

    // stage step t's two 8KB windows: 2 contiguous 1KB DMAs per wave (linear dest, m104)
#define STAGE2(t, par)                                                                   \
    {                                                                                    \
        const unsigned short* s0 = WhTp3 + ((size_t)(ccbase + 2*(t))     * 512 + wave * 64 + lane) * 8; \
        const unsigned short* s1 = WhTp3 + ((size_t)(ccbase + 2*(t) + 1) * 512 + wave * 64 + lane) * 8; \
        __builtin_amdgcn_global_load_lds(s0, &bbuf[par][0][wave * 512], 16, 0, 0);       \
        __builtin_amdgcn_global_load_lds(s1, &bbuf[par][1][wave * 512], 16, 0, 0);       \
    }

    // compute one 64-col window from staged buffer `wb` with bit-shift base `sh`
#define WINDOW(cc, wb, sh, W0, W1, W2, W3, u0, u1, u2, u3)                              \
    {                                                                                   \
        const unsigned short* lb = &bbuf[par][wb][lane * 64];                           \
        const bf16x8 B00 = *(const bf16x8*)(lb + ((0 ^ (lane & 7)) * 8));               \
        const bf16x8 B01 = *(const bf16x8*)(lb + ((1 ^ (lane & 7)) * 8));               \
        const bf16x8 B10 = *(const bf16x8*)(lb + ((2 ^ (lane & 7)) * 8));               \
        const bf16x8 B11 = *(const bf16x8*)(lb + ((3 ^ (lane & 7)) * 8));               \
        const bf16x8 B20 = *(const bf16x8*)(lb + ((4 ^ (lane & 7)) * 8));               \
        const bf16x8 B21 = *(const bf16x8*)(lb + ((5 ^ (lane & 7)) * 8));               \
        const bf16x8 B30 = *(const bf16x8*)(lb + ((6 ^ (lane & 7)) * 8));               \
        const bf16x8 B31 = *(const bf16x8*)(lb + ((7 ^ (lane & 7)) * 8));               \
        bf16x8 af0, af1;                                                                \
        af0[0] = (short)f2bf(pb(u0,  0, W0.x, wh1v, lsum));                             \
        af0[1] = (short)f2bf(pb(u1,  0, W0.y, wh1v, lsum));                             \
        af0[2] = (short)f2bf(pb(u2,  0, W0.z, wh1v, lsum));                             \
        af0[3] = (short)f2bf(pb(u3,  0, W0.w, wh1v, lsum));                             \
        af0[4] = (short)f2bf(pb(u0,  4, W1.x, wh1v, lsum));                             \
        af0[5] = (short)f2bf(pb(u1,  4, W1.y, wh1v, lsum));                             \
        af0[6] = (short)f2bf(pb(u2,  4, W1.z, wh1v, lsum));                             \
        af0[7] = (short)f2bf(pb(u3,  4, W1.w, wh1v, lsum));                             \
        af1[0] = (short)f2bf(pb(u0,  8, W2.x, wh1v, lsum));                             \
        af1[1] = (short)f2bf(pb(u1,  8, W2.y, wh1v, lsum));                             \
        af1[2] = (short)f2bf(pb(u2,  8, W2.z, wh1v, lsum));                             \
        af1[3] = (short)f2bf(pb(u3,  8, W2.w, wh1v, lsum));                             \
        af1[4] = (short)f2bf(pb(u0, 12, W3.x, wh1v, lsum));                             \
        af1[5] = (short)f2bf(pb(u1, 12, W3.y, wh1v, lsum));                             \
        af1[6] = (short)f2bf(pb(u2, 12, W3.z, wh1v, lsum));                             \
        af1[7] = (short)f2bf(pb(u3, 12, W3.w, wh1v, lsum));                             \
        acc0 = __builtin_amdgcn_mfma_f32_16x16x32_bf16(af0, B00, acc0, 0, 0, 0);        \
        acc1 = __builtin_amdgcn_mfma_f32_16x16x32_bf16(af0, B10, acc1, 0, 0, 0);        \
        acc2 = __builtin_amdgcn_mfma_f32_16x16x32_bf16(af0, B20, acc2, 0, 0, 0);        \
        acc3 = __builtin_amdgcn_mfma_f32_16x16x32_bf16(af0, B30, acc3, 0, 0, 0);        \
        acc0 = __builtin_amdgcn_mfma_f32_16x16x32_bf16(af1, B01, acc0, 0, 0, 0);        \
        acc1 = __builtin_amdgcn_mfma_f32_16x16x32_bf16(af1, B11, acc1, 0, 0, 0);        \
        acc2 = __builtin_amdgcn_mfma_f32_16x16x32_bf16(af1, B21, acc2, 0, 0, 0);        \
        acc3 = __builtin_amdgcn_mfma_f32_16x16x32_bf16(af1, B31, acc3, 0, 0, 0);        \
    }

    STAGE2(0, 0);
    __syncthreads();

    #pragma unroll 2
    for (int t = 0; t < NSTEP; ++t) {
        const int par = t & 1;
        const int cc0 = ccbase + 2 * t;    // even; cc0 and cc0+1 share q
        const int q    = cc0 >> 2;
        const int sub0 = cc0 & 3;          // 0 or 2

        // ---- register loads FIRST (older than the DMAs) ----
        const unsigned long long* wp_ = bits + (((size_t)strip * 32 + q) * 16 + i16) * 4;
        const ulonglong2 Wd01 = *(const ulonglong2*)(wp_);
        const ulonglong2 Wd23 = *(const ulonglong2*)(wp_ + 2);

        const float* wpa = Wh2 + cc0 * 64 + g * 4;
        const float4 Wa0 = *(const float4*)(wpa);
        const float4 Wa1 = *(const float4*)(wpa + 16);
        const float4 Wa2 = *(const float4*)(wpa + 32);
        const float4 Wa3 = *(const float4*)(wpa + 48);
        const float* wpb = wpa + 64;
        const float4 Wb0 = *(const float4*)(wpb);
        const float4 Wb1 = *(const float4*)(wpb + 16);
        const float4 Wb2 = *(const float4*)(wpb + 32);
        const float4 Wb3 = *(const float4*)(wpb + 48);

        // ---- staging DMAs LAST (youngest vmem -> stay in flight through compute) ----
        if (t + 1 < NSTEP) STAGE2(t + 1, par ^ 1);
        __builtin_amdgcn_sched_barrier(0);

        // window A (sub0), window B (sub0+1)
        {
            const int shA = sub0 * 16 + g;
            const unsigned uA0 = (unsigned)(Wd01.x >> shA);
            const unsigned uA1 = (unsigned)(Wd01.y >> shA);
            const unsigned uA2 = (unsigned)(Wd23.x >> shA);
            const unsigned uA3 = (unsigned)(Wd23.y >> shA);
            WINDOW(cc0, 0, shA, Wa0, Wa1, Wa2, Wa3, uA0, uA1, uA2, uA3);
            const int shB = shA + 16;
            const unsigned uB0 = (unsigned)(Wd01.x >> shB);
            const unsigned uB1 = (unsigned)(Wd01.y >> shB);
            const unsigned uB2 = (unsigned)(Wd23.x >> shB);
            const unsigned uB3 = (unsigned)(Wd23.y >> shB);
            WINDOW(cc0 + 1, 1, shB, Wb0, Wb1, Wb2, Wb3, uB0, uB1, uB2, uB3);
        }

        if (t + 1 < NSTEP) __syncthreads();   // next step's windows landed
    }
#undef STAGE2
#undef WINDOW

    // per-row lsum: combine the 4 g-subgroups (xor 16/32 varies g only)
    lsum += __shfl_xor(lsum, 16);
    lsum += __shfl_xor(lsum, 32);

    // D layout (m89): row = g*4 + r (wave-private rows -> direct partial writes)
    #pragma unroll
    for (int r = 0; r < 4; ++r) {
        const int row = Rw + g * 4 + r;
        float* pr = pacc + ((size_t)slice * N_NODES + row) * D_OUT + i16;
        pr[ 0] = acc0[r];
        pr[16] = acc1[r];
        pr[32] = acc2[r];
        pr[48] = acc3[r];
    }
    if (lane < 16) plsum[(size_t)slice * N_NODES + Rw + lane] = lsum;
}

// ---------------- Kernel C: sum KSPLIT partials, normalize, ELU ----------------
__global__ __launch_bounds__(256) void k_finish(const float* __restrict__ pacc,
                                                const float* __restrict__ plsum,
                                                float* __restrict__ out) {
    const int idx = blockIdx.x * 256 + threadIdx.x;
    const int row = idx >> 4;
    const int tf4 = (idx & 15) * 4;
    float4 s = {0.f, 0.f, 0.f, 0.f};
    float L = 0.f;
    #pragma unroll
    for (int k = 0; k < KSPLIT; ++k) {
        float4 v = *(const float4*)&pacc[((size_t)k * N_NODES + row) * D_OUT + tf4];
        s.x += v.x; s.y += v.y; s.z += v.z; s.w += v.w;
        L += plsum[(size_t)k * N_NODES + row];
    }
    const float inv = (L > 0.f) ? 1.f / L : 0.f;
    float4 o;
    o.x = s.x * inv; o.y = s.y * inv; o.z = s.z * inv; o.w = s.w * inv;
    o.x = (o.x > 0.f) ? o.x : (__expf(o.x) - 1.f);
    o.y = (o.y > 0.f) ? o.y : (__expf(o.y) - 1.f);
    o.z = (o.z > 0.f) ? o.z : (__expf(o.z) - 1.f);
    o.w = (o.w > 0.f) ? o.w : (__expf(o.w) - 1.f);
    *(float4*)&out[(size_t)row * D_OUT + tf4] = o;
}

extern "C" void kernel_launch(void* const* d_in, const int* in_sizes, int n_in,
                              void* d_out, int out_size, void* d_ws, size_t ws_size,
                              hipStream_t stream) {
    const float* h    = (const float*)d_in[0];
    const float* mask = (const float*)d_in[1];
    // d_in[2] = lamda: unused (dischange==0 makes the mask-update a no-op)
    const float* W    = (const float*)d_in[3];
    const float* a    = (const float*)d_in[4];
    float* out = (float*)d_out;

    // ws: WhTp3 1MB | Wh1 32KB | Wh2 32KB | bits 8MB | pacc 16MB | plsum 256KB
    unsigned short* WhTp3 = (unsigned short*)d_ws;
    float* Wh1 = (float*)((char*)d_ws + (size_t)D_OUT * N_NODES * sizeof(unsigned short));
    float* Wh2 = Wh1 + N_NODES;
    unsigned long long* bitsw = (unsigned long long*)(Wh2 + N_NODES);
    float* pacc = (float*)(bitsw + (size_t)N_NODES * (N_NODES / 64));
    float* plsum = pacc + (size_t)KSPLIT * N_NODES * D_OUT;

    k_front<<<GEMM_BLOCKS + N_NODES / 4, 256, 0, stream>>>(h, W, a, mask, WhTp3, Wh1, Wh2, bitsw);
    k_attn<<<(N_NODES / 128) * KSPLIT, 512, 0, stream>>>(bitsw, WhTp3, Wh1, Wh2, pacc, plsum);
    k_finish<<<(N_NODES * D_OUT / 4) / 256, 256, 0, stream>>>(pacc, plsum, out);
}

// Round 20
// 108.148 us; speedup vs baseline: 1.4279x; 1.4279x over previous
//
#include <hip/hip_runtime.h>

#define N_NODES 8192
#define D_IN 512
#define D_OUT 64
#define LRELU_ALPHA 0.2f
#define KSPLIT 8
#define KSLICE (N_NODES / KSPLIT)    // 1024 cols per attn block
#define NCHUNK (KSLICE / 64)         // 16 chunks of 64 cols
#define GEMM_BLOCKS (N_NODES / 32)   // 256

typedef __attribute__((ext_vector_type(8))) short bf16x8;
typedef __attribute__((ext_vector_type(4))) float f32x4;

__device__ __forceinline__ unsigned short f2bf(float x) {
    unsigned u = __float_as_uint(x);
    u += 0x7fffu + ((u >> 16) & 1u);   // round-to-nearest-even
    return (unsigned short)(u >> 16);
}

// bit-gated p: e = lrelu(wh1+w2); p = bit ? exp(e) : 0
__device__ __forceinline__ float pb(unsigned bits, int pos, float w2v, float wh1v, float& lsum) {
    float e = wh1v + w2v;
    e = fmaxf(e, LRELU_ALPHA * e);
    float p = ((bits >> pos) & 1u) ? __expf(e) : 0.f;
    lsum += p;
    return p;
}

// ---------------- Kernel A (fused front): gemm blocks [0,256) + maskbits blocks [256,2304) ----------------
// (byte-identical to R18's passing version)
__global__ __launch_bounds__(256) void k_front(const float* __restrict__ h,
                                               const float* __restrict__ W,
                                               const float* __restrict__ a,
                                               const float* __restrict__ mask,
                                               unsigned short* __restrict__ WhTp3,
                                               float* __restrict__ Wh1,
                                               float* __restrict__ Wh2,
                                               unsigned long long* __restrict__ bits) {
    __shared__ float hs[32][68];
    __shared__ float Ws[64][64];

    if (blockIdx.x >= GEMM_BLOCKS) {
        const int bid = blockIdx.x - GEMM_BLOCKS;
        const int wave = threadIdx.x >> 6;
        const int lane = threadIdx.x & 63;
        const int row = bid * 4 + wave;
        const float4* m4 = (const float4*)(mask + (size_t)row * N_NODES);
        const int strip = row >> 4;
        const int r16 = row & 15;
        #pragma unroll 4
        for (int q = 0; q < 32; ++q) {
            const float4 v = m4[q * 64 + lane];
            const unsigned long long b0 = __ballot(v.x > 0.f);
            const unsigned long long b1 = __ballot(v.y > 0.f);
            const unsigned long long b2 = __ballot(v.z > 0.f);
            const unsigned long long b3 = __ballot(v.w > 0.f);
            if (lane == 0) {
                unsigned long long* dst = bits + (((size_t)strip * 32 + q) * 16 + r16) * 4;
                ulonglong2 t0; t0.x = b0; t0.y = b1;
                ulonglong2 t1; t1.x = b2; t1.y = b3;
                *(ulonglong2*)(dst)     = t0;
                *(ulonglong2*)(dst + 2) = t1;
            }
        }
        return;
    }

    const int tid = threadIdx.x;
    const int r0 = blockIdx.x * 32;
    const int tf = tid & 15;
    const int tr = tid >> 4;
    float acc[2][4] = {{0.f,0.f,0.f,0.f},{0.f,0.f,0.f,0.f}};

    for (int kc = 0; kc < D_IN; kc += 64) {
        {
            int rr = tid >> 4;
            int cc = (tid & 15) * 4;
            float4 v0 = *(const float4*)&h[(size_t)(r0 + rr) * D_IN + kc + cc];
            float4 v1 = *(const float4*)&h[(size_t)(r0 + rr + 16) * D_IN + kc + cc];
            *(float4*)&hs[rr][cc] = v0;
            *(float4*)&hs[rr + 16][cc] = v1;
        }
        #pragma unroll
        for (int p = 0; p < 4; ++p) {
            int kk = (tid >> 4) + p * 16;
            int cc = (tid & 15) * 4;
            *(float4*)&Ws[kk][cc] = *(const float4*)&W[(size_t)(kc + kk) * D_OUT + cc];
        }
        __syncthreads();
        #pragma unroll
        for (int k = 0; k < 64; k += 4) {
            float4 a0 = *(const float4*)&hs[tr*2][k];
            float4 a1 = *(const float4*)&hs[tr*2+1][k];
            float av0[4] = {a0.x, a0.y, a0.z, a0.w};
            float av1[4] = {a1.x, a1.y, a1.z, a1.w};
            #pragma unroll
            for (int kk = 0; kk < 4; ++kk) {
                float4 b = *(const float4*)&Ws[k+kk][tf*4];
                acc[0][0] += av0[kk]*b.x; acc[0][1] += av0[kk]*b.y;
                acc[0][2] += av0[kk]*b.z; acc[0][3] += av0[kk]*b.w;
                acc[1][0] += av1[kk]*b.x; acc[1][1] += av1[kk]*b.y;
                acc[1][2] += av1[kk]*b.z; acc[1][3] += av1[kk]*b.w;
            }
        }
        __syncthreads();
    }
    const int orow = r0 + tr*2;   // even

    {
        const int cc  = orow >> 6;
        const int cw  = orow & 63;
        const int hh  = cw >> 5;
        const int rem = cw & 31;
        const int jhi = rem >> 4;
        const int gg  = (rem >> 2) & 3;
        const int jlo = cw & 3;          // even
        const int j   = jhi * 4 + jlo;
        #pragma unroll
        for (int k = 0; k < 4; ++k) {
            const int f = tf * 4 + k;
            const int L = gg * 16 + (f & 15);
            const int s = (2 * (f >> 4) + hh) ^ (L & 7);
            const size_t sidx = ((size_t)(cc * 64 + L) * 8 + s) * 8 + j;
            unsigned v = (unsigned)f2bf(acc[0][k]) | ((unsigned)f2bf(acc[1][k]) << 16);
            *(unsigned*)&WhTp3[sidx] = v;
        }
    }

    float a1v[4], a2v[4];
    #pragma unroll
    for (int k = 0; k < 4; ++k) { a1v[k] = a[tf*4 + k]; a2v[k] = a[64 + tf*4 + k]; }
    float s1 = 0.f, t1 = 0.f, s2 = 0.f, t2 = 0.f;
    #pragma unroll
    for (int k = 0; k < 4; ++k) {
        s1 += acc[0][k] * a1v[k];
        t1 += acc[1][k] * a1v[k];
        s2 += acc[0][k] * a2v[k];
        t2 += acc[1][k] * a2v[k];
    }
    #pragma unroll
    for (int d = 1; d < 16; d <<= 1) {
        s1 += __shfl_xor(s1, d);
        t1 += __shfl_xor(t1, d);
        s2 += __shfl_xor(s2, d);
        t2 += __shfl_xor(t2, d);
    }
    if (tf == 0) {
        Wh1[orow] = s1; Wh1[orow + 1] = t1;
        Wh2[orow] = s2; Wh2[orow + 1] = t2;
    }
}

// ---------------- Kernel B: R18's block-staged attn + ONE fix: reg loads issued before STAGE ----------------
// Identical structure to R18 (105.3us): 512 blocks = 64 rowgroups x 8 slices, 8 waves
// row-split, one 8KB B-window staged per chunk via 1KB-contiguous global_load_lds/wave,
// 16KB LDS dbuf. Single edit: bits/Wh2 register loads are issued BEFORE STAGE(c+1), so
// the DMAs are the youngest vmem ops and the compute's compiler-inserted waits for
// bits/Wh2 leave the staging in flight (R9 in-order-retire lesson). Registers loaded
// here are consumed in the same iteration -> no added live range.
__global__ __launch_bounds__(512, 4) void k_attn(const unsigned long long* __restrict__ bits,
                                                 const unsigned short* __restrict__ WhTp3,
                                                 const float* __restrict__ Wh1,
                                                 const float* __restrict__ Wh2,
                                                 float* __restrict__ pacc,
                                                 float* __restrict__ plsum) {
    __shared__ unsigned short bbuf[2][4096];   // 2 x 8KB B-window double buffer

    const int tid  = threadIdx.x;
    const int wave = tid >> 6;       // 0..7: strip within rowgroup
    const int lane = tid & 63;
    const int i16 = lane & 15;
    const int g   = lane >> 4;
    const int rg    = blockIdx.x >> 3;
    const int slice = blockIdx.x & 7;
    const int Rw    = rg * 128 + wave * 16;     // this wave's 16 rows
    const int strip = rg * 8 + wave;            // global 16-row strip index
    const int ccbase = slice * NCHUNK;          // first 64-col window

    const float wh1v = Wh1[Rw + i16];

    f32x4 acc0 = {0.f,0.f,0.f,0.f}, acc1 = {0.f,0.f,0.f,0.f};
    f32x4 acc2 = {0.f,0.f,0.f,0.f}, acc3 = {0.f,0.f,0.f,0.f};
    float lsum = 0.f;

    // stage chunk c's 8KB B-window: one contiguous 1KB DMA per wave (linear dest, m104)
#define STAGE(c, par)                                                                   \
    {                                                                                   \
        const unsigned short* src = WhTp3 + ((size_t)(ccbase + (c)) * 512 + wave * 64 + lane) * 8; \
        __builtin_amdgcn_global_load_lds(src, &bbuf[par][wave * 512], 16, 0, 0);        \
    }

    STAGE(0, 0);
    __syncthreads();

    #pragma unroll 2
    for (int c = 0; c < NCHUNK; ++c) {
        const int par = c & 1;
        const int cc = ccbase + c;

        // ---- register loads FIRST (older than the staging DMAs) ----
        const int q   = cc >> 2;
        const int sub = cc & 3;
        const int sh  = sub * 16 + g;
        const unsigned long long* wp_ = bits + (((size_t)strip * 32 + q) * 16 + i16) * 4;
        const ulonglong2 Wd01 = *(const ulonglong2*)(wp_);
        const ulonglong2 Wd23 = *(const ulonglong2*)(wp_ + 2);

        const float* wp = Wh2 + cc * 64 + g * 4;
        const float4 W0 = *(const float4*)(wp);
        const float4 W1 = *(const float4*)(wp + 16);
        const float4 W2 = *(const float4*)(wp + 32);
        const float4 W3 = *(const float4*)(wp + 48);

        // ---- staging DMA LAST (youngest vmem -> stays in flight through compute) ----
        if (c + 1 < NCHUNK) STAGE(c + 1, par ^ 1);
        __builtin_amdgcn_sched_barrier(0);

        const unsigned u0 = (unsigned)(Wd01.x >> sh);
        const unsigned u1 = (unsigned)(Wd01.y >> sh);
        const unsigned u2 = (unsigned)(Wd23.x >> sh);
        const unsigned u3 = (unsigned)(Wd23.y >> sh);

        // B frags from LDS: lane base L*128 bytes, slot (2q+h)^(L&7)
        const unsigned short* lb = &bbuf[par][lane * 64];
        const bf16x8 B00 = *(const bf16x8*)(lb + ((0 ^ (lane & 7)) * 8));
        const bf16x8 B01 = *(const bf16x8*)(lb + ((1 ^ (lane & 7)) * 8));
        const bf16x8 B10 = *(const bf16x8*)(lb + ((2 ^ (lane & 7)) * 8));
        const bf16x8 B11 = *(const bf16x8*)(lb + ((3 ^ (lane & 7)) * 8));
        const bf16x8 B20 = *(const bf16x8*)(lb + ((4 ^ (lane & 7)) * 8));
        const bf16x8 B21 = *(const bf16x8*)(lb + ((5 ^ (lane & 7)) * 8));
        const bf16x8 B30 = *(const bf16x8*)(lb + ((6 ^ (lane & 7)) * 8));
        const bf16x8 B31 = *(const bf16x8*)(lb + ((7 ^ (lane & 7)) * 8));

        // element (m, d): col = cc*64 + m*16 + g*4 + d; gate = bit 4m of u_d
        bf16x8 af0, af1;
        af0[0] = (short)f2bf(pb(u0,  0, W0.x, wh1v, lsum));
        af0[1] = (short)f2bf(pb(u1,  0, W0.y, wh1v, lsum));
        af0[2] = (short)f2bf(pb(u2,  0, W0.z, wh1v, lsum));
        af0[3] = (short)f2bf(pb(u3,  0, W0.w, wh1v, lsum));
        af0[4] = (short)f2bf(pb(u0,  4, W1.x, wh1v, lsum));
        af0[5] = (short)f2bf(pb(u1,  4, W1.y, wh1v, lsum));
        af0[6] = (short)f2bf(pb(u2,  4, W1.z, wh1v, lsum));
        af0[7] = (short)f2bf(pb(u3,  4, W1.w, wh1v, lsum));
        af1[0] = (short)f2bf(pb(u0,  8, W2.x, wh1v, lsum));
        af1[1] = (short)f2bf(pb(u1,  8, W2.y, wh1v, lsum));
        af1[2] = (short)f2bf(pb(u2,  8, W2.z, wh1v, lsum));
        af1[3] = (short)f2bf(pb(u3,  8, W2.w, wh1v, lsum));
        af1[4] = (short)f2bf(pb(u0, 12, W3.x, wh1v, lsum));
        af1[5] = (short)f2bf(pb(u1, 12, W3.y, wh1v, lsum));
        af1[6] = (short)f2bf(pb(u2, 12, W3.z, wh1v, lsum));
        af1[7] = (short)f2bf(pb(u3, 12, W3.w, wh1v, lsum));

        acc0 = __builtin_amdgcn_mfma_f32_16x16x32_bf16(af0, B00, acc0, 0, 0, 0);
        acc1 = __builtin_amdgcn_mfma_f32_16x16x32_bf16(af0, B10, acc1, 0, 0, 0);
        acc2 = __builtin_amdgcn_mfma_f32_16x16x32_bf16(af0, B20, acc2, 0, 0, 0);
        acc3 = __builtin_amdgcn_mfma_f32_16x16x32_bf16(af0, B30, acc3, 0, 0, 0);
        acc0 = __builtin_amdgcn_mfma_f32_16x16x32_bf16(af1, B01, acc0, 0, 0, 0);
        acc1 = __builtin_amdgcn_mfma_f32_16x16x32_bf16(af1, B11, acc1, 0, 0, 0);
        acc2 = __builtin_amdgcn_mfma_f32_16x16x32_bf16(af1, B21, acc2, 0, 0, 0);
        acc3 = __builtin_amdgcn_mfma_f32_16x16x32_bf16(af1, B31, acc3, 0, 0, 0);

        if (c + 1 < NCHUNK) __syncthreads();   // STAGE(c+1) drained; bbuf[par] free for c+2
    }
#undef STAGE

    // per-row lsum: combine the 4 g-subgroups (xor 16/32 varies g only)
    lsum += __shfl_xor(lsum, 16);
    lsum += __shfl_xor(lsum, 32);

    // D layout (m89): row = g*4 + r (wave-private rows -> direct partial writes)
    #pragma unroll
    for (int r = 0; r < 4; ++r) {
        const int row = Rw + g * 4 + r;
        float* pr = pacc + ((size_t)slice * N_NODES + row) * D_OUT + i16;
        pr[ 0] = acc0[r];
        pr[16] = acc1[r];
        pr[32] = acc2[r];
        pr[48] = acc3[r];
    }
    if (lane < 16) plsum[(size_t)slice * N_NODES + Rw + lane] = lsum;
}

// ---------------- Kernel C: sum KSPLIT partials, normalize, ELU ----------------
__global__ __launch_bounds__(256) void k_finish(const float* __restrict__ pacc,
                                                const float* __restrict__ plsum,
                                                float* __restrict__ out) {
    const int idx = blockIdx.x * 256 + threadIdx.x;
    const int row = idx >> 4;
    const int tf4 = (idx & 15) * 4;
    float4 s = {0.f, 0.f, 0.f, 0.f};
    float L = 0.f;
    #pragma unroll
    for (int k = 0; k < KSPLIT; ++k) {
        float4 v = *(const float4*)&pacc[((size_t)k * N_NODES + row) * D_OUT + tf4];
        s.x += v.x; s.y += v.y; s.z += v.z; s.w += v.w;
        L += plsum[(size_t)k * N_NODES + row];
    }
    const float inv = (L > 0.f) ? 1.f / L : 0.f;
    float4 o;
    o.x = s.x * inv; o.y = s.y * inv; o.z = s.z * inv; o.w = s.w * inv;
    o.x = (o.x > 0.f) ? o.x : (__expf(o.x) - 1.f);
    o.y = (o.y > 0.f) ? o.y : (__expf(o.y) - 1.f);
    o.z = (o.z > 0.f) ? o.z : (__expf(o.z) - 1.f);
    o.w = (o.w > 0.f) ? o.w : (__expf(o.w) - 1.f);
    *(float4*)&out[(size_t)row * D_OUT + tf4] = o;
}

extern "C" void kernel_launch(void* const* d_in, const int* in_sizes, int n_in,
                              void* d_out, int out_size, void* d_ws, size_t ws_size,
                              hipStream_t stream) {
    const float* h    = (const float*)d_in[0];
    const float* mask = (const float*)d_in[1];
    // d_in[2] = lamda: unused (dischange==0 makes the mask-update a no-op)
    const float* W    = (const float*)d_in[3];
    const float* a    = (const float*)d_in[4];
    float* out = (float*)d_out;

    // ws: WhTp3 1MB | Wh1 32KB | Wh2 32KB | bits 8MB | pacc 16MB | plsum 256KB
    unsigned short* WhTp3 = (unsigned short*)d_ws;
    float* Wh1 = (float*)((char*)d_ws + (size_t)D_OUT * N_NODES * sizeof(unsigned short));
    float* Wh2 = Wh1 + N_NODES;
    unsigned long long* bitsw = (unsigned long long*)(Wh2 + N_NODES);
    float* pacc = (float*)(bitsw + (size_t)N_NODES * (N_NODES / 64));
    float* plsum = pacc + (size_t)KSPLIT * N_NODES * D_OUT;

    k_front<<<GEMM_BLOCKS + N_NODES / 4, 256, 0, stream>>>(h, W, a, mask, WhTp3, Wh1, Wh2, bitsw);
    k_attn<<<(N_NODES / 128) * KSPLIT, 512, 0, stream>>>(bitsw, WhTp3, Wh1, Wh2, pacc, plsum);
    k_finish<<<(N_NODES * D_OUT / 4) / 256, 256, 0, stream>>>(pacc, plsum, out);
}

// Round 21
// 105.755 us; speedup vs baseline: 1.4602x; 1.0226x over previous
//
#include <hip/hip_runtime.h>

#define N_NODES 8192
#define D_IN 512
#define D_OUT 64
#define LRELU_ALPHA 0.2f
#define KSPLIT 8
#define KSLICE (N_NODES / KSPLIT)    // 1024 cols per attn block
#define NCHUNK (KSLICE / 64)         // 16 chunks of 64 cols
#define GEMM_BLOCKS (N_NODES / 32)   // 256

typedef __attribute__((ext_vector_type(8))) short bf16x8;
typedef __attribute__((ext_vector_type(4))) float f32x4;

__device__ __forceinline__ unsigned short f2bf(float x) {
    unsigned u = __float_as_uint(x);
    u += 0x7fffu + ((u >> 16) & 1u);   // round-to-nearest-even
    return (unsigned short)(u >> 16);
}

// bit-gated p: e = lrelu(wh1+w2); p = bit ? exp(e) : 0
__device__ __forceinline__ float pb(unsigned bits, int pos, float w2v, float wh1v, float& lsum) {
    float e = wh1v + w2v;
    e = fmaxf(e, LRELU_ALPHA * e);
    float p = ((bits >> pos) & 1u) ? __expf(e) : 0.f;
    lsum += p;
    return p;
}

// ---------------- Kernel A (fused front): gemm blocks [0,256) + maskbits blocks [256,2304) ----------------
// (byte-identical to R18's passing version)
__global__ __launch_bounds__(256) void k_front(const float* __restrict__ h,
                                               const float* __restrict__ W,
                                               const float* __restrict__ a,
                                               const float* __restrict__ mask,
                                               unsigned short* __restrict__ WhTp3,
                                               float* __restrict__ Wh1,
                                               float* __restrict__ Wh2,
                                               unsigned long long* __restrict__ bits) {
    __shared__ float hs[32][68];
    __shared__ float Ws[64][64];

    if (blockIdx.x >= GEMM_BLOCKS) {
        const int bid = blockIdx.x - GEMM_BLOCKS;
        const int wave = threadIdx.x >> 6;
        const int lane = threadIdx.x & 63;
        const int row = bid * 4 + wave;
        const float4* m4 = (const float4*)(mask + (size_t)row * N_NODES);
        const int strip = row >> 4;
        const int r16 = row & 15;
        #pragma unroll 4
        for (int q = 0; q < 32; ++q) {
            const float4 v = m4[q * 64 + lane];
            const unsigned long long b0 = __ballot(v.x > 0.f);
            const unsigned long long b1 = __ballot(v.y > 0.f);
            const unsigned long long b2 = __ballot(v.z > 0.f);
            const unsigned long long b3 = __ballot(v.w > 0.f);
            if (lane == 0) {
                unsigned long long* dst = bits + (((size_t)strip * 32 + q) * 16 + r16) * 4;
                ulonglong2 t0; t0.x = b0; t0.y = b1;
                ulonglong2 t1; t1.x = b2; t1.y = b3;
                *(ulonglong2*)(dst)     = t0;
                *(ulonglong2*)(dst + 2) = t1;
            }
        }
        return;
    }

    const int tid = threadIdx.x;
    const int r0 = blockIdx.x * 32;
    const int tf = tid & 15;
    const int tr = tid >> 4;
    float acc[2][4] = {{0.f,0.f,0.f,0.f},{0.f,0.f,0.f,0.f}};

    for (int kc = 0; kc < D_IN; kc += 64) {
        {
            int rr = tid >> 4;
            int cc = (tid & 15) * 4;
            float4 v0 = *(const float4*)&h[(size_t)(r0 + rr) * D_IN + kc + cc];
            float4 v1 = *(const float4*)&h[(size_t)(r0 + rr + 16) * D_IN + kc + cc];
            *(float4*)&hs[rr][cc] = v0;
            *(float4*)&hs[rr + 16][cc] = v1;
        }
        #pragma unroll
        for (int p = 0; p < 4; ++p) {
            int kk = (tid >> 4) + p * 16;
            int cc = (tid & 15) * 4;
            *(float4*)&Ws[kk][cc] = *(const float4*)&W[(size_t)(kc + kk) * D_OUT + cc];
        }
        __syncthreads();
        #pragma unroll
        for (int k = 0; k < 64; k += 4) {
            float4 a0 = *(const float4*)&hs[tr*2][k];
            float4 a1 = *(const float4*)&hs[tr*2+1][k];
            float av0[4] = {a0.x, a0.y, a0.z, a0.w};
            float av1[4] = {a1.x, a1.y, a1.z, a1.w};
            #pragma unroll
            for (int kk = 0; kk < 4; ++kk) {
                float4 b = *(const float4*)&Ws[k+kk][tf*4];
                acc[0][0] += av0[kk]*b.x; acc[0][1] += av0[kk]*b.y;
                acc[0][2] += av0[kk]*b.z; acc[0][3] += av0[kk]*b.w;
                acc[1][0] += av1[kk]*b.x; acc[1][1] += av1[kk]*b.y;
                acc[1][2] += av1[kk]*b.z; acc[1][3] += av1[kk]*b.w;
            }
        }
        __syncthreads();
    }
    const int orow = r0 + tr*2;   // even

    {
        const int cc  = orow >> 6;
        const int cw  = orow & 63;
        const int hh  = cw >> 5;
        const int rem = cw & 31;
        const int jhi = rem >> 4;
        const int gg  = (rem >> 2) & 3;
        const int jlo = cw & 3;          // even
        const int j   = jhi * 4 + jlo;
        #pragma unroll
        for (int k = 0; k < 4; ++k) {
            const int f = tf * 4 + k;
            const int L = gg * 16 + (f & 15);
            const int s = (2 * (f >> 4) + hh) ^ (L & 7);
            const size_t sidx = ((size_t)(cc * 64 + L) * 8 + s) * 8 + j;
            unsigned v = (unsigned)f2bf(acc[0][k]) | ((unsigned)f2bf(acc[1][k]) << 16);
            *(unsigned*)&WhTp3[sidx] = v;
        }
    }

    float a1v[4], a2v[4];
    #pragma unroll
    for (int k = 0; k < 4; ++k) { a1v[k] = a[tf*4 + k]; a2v[k] = a[64 + tf*4 + k]; }
    float s1 = 0.f, t1 = 0.f, s2 = 0.f, t2 = 0.f;
    #pragma unroll
    for (int k = 0; k < 4; ++k) {
        s1 += acc[0][k] * a1v[k];
        t1 += acc[1][k] * a1v[k];
        s2 += acc[0][k] * a2v[k];
        t2 += acc[1][k] * a2v[k];
    }
    #pragma unroll
    for (int d = 1; d < 16; d <<= 1) {
        s1 += __shfl_xor(s1, d);
        t1 += __shfl_xor(t1, d);
        s2 += __shfl_xor(s2, d);
        t2 += __shfl_xor(t2, d);
    }
    if (tf == 0) {
        Wh1[orow] = s1; Wh1[orow + 1] = t1;
        Wh2[orow] = s2; Wh2[orow + 1] = t2;
    }
}

// ---------------- Kernel B: R18 structure + T3/T4 counted-vmcnt pipeline ----------------
// The 16 __syncthreads drains were the last structural stall: each forced vmcnt(0) on
// the staged DMA. Fix (the m218-proven T4 pattern): make the loop's vmem stream DMA-ONLY
// (bits 16KB + Wh2 4KB hoisted to LDS in a one-time prologue), triple-buffer the B
// windows, and sync with raw s_barrier + counted s_waitcnt vmcnt(1) -- one DMA always
// in flight, never drained until the final chunk. Correctness: passing the barrier
// implies every wave executed its vmcnt(1), so DMA(c) has globally landed; buffer
// (c+2)%3 was last read in iter c-1, protected by the iter-c barrier.
__global__ __launch_bounds__(512, 4) void k_attn(const unsigned long long* __restrict__ bits,
                                                 const unsigned short* __restrict__ WhTp3,
                                                 const float* __restrict__ Wh1,
                                                 const float* __restrict__ Wh2,
                                                 float* __restrict__ pacc,
                                                 float* __restrict__ plsum) {
    __shared__ unsigned short bbuf[3][4096];              // 24 KB: triple-buffered B windows
    __shared__ unsigned long long bitlds[8][4][16][4];    // 16 KB: block's bit tiles
    __shared__ float wh2lds[KSLICE];                      // 4 KB: slice's Wh2

    const int tid  = threadIdx.x;
    const int wave = tid >> 6;       // 0..7: strip within rowgroup
    const int lane = tid & 63;
    const int i16 = lane & 15;
    const int g   = lane >> 4;
    const int rg    = blockIdx.x >> 3;
    const int slice = blockIdx.x & 7;
    const int Rw    = rg * 128 + wave * 16;     // this wave's 16 rows
    const int strip = rg * 8 + wave;            // global 16-row strip index
    const int ccbase = slice * NCHUNK;          // first 64-col window

    const float wh1v = Wh1[Rw + i16];

    // ---- prologue: hoist bits + Wh2 into LDS (one-time; retires before the loop) ----
    {
        // wave w stages its strip's 4 q-tiles: lane (q = lane>>4, r = lane&15) moves 32B
        const int q = lane >> 4, r = lane & 15;
        const unsigned long long* src = bits + (((size_t)strip * 32 + slice * 4 + q) * 16 + r) * 4;
        *(ulonglong2*)&bitlds[wave][q][r][0] = *(const ulonglong2*)(src);
        *(ulonglong2*)&bitlds[wave][q][r][2] = *(const ulonglong2*)(src + 2);
        if (tid < 256) {
            *(float4*)&wh2lds[tid * 4] = *(const float4*)&Wh2[ccbase * 64 + tid * 4];
        }
    }
    __syncthreads();   // LDS tables visible (also drains the prologue global loads)

    f32x4 acc0 = {0.f,0.f,0.f,0.f}, acc1 = {0.f,0.f,0.f,0.f};
    f32x4 acc2 = {0.f,0.f,0.f,0.f}, acc3 = {0.f,0.f,0.f,0.f};
    float lsum = 0.f;

    // stage chunk c's 8KB B-window into buffer b: one contiguous 1KB DMA per wave
#define STAGE(c, b)                                                                     \
    {                                                                                   \
        const unsigned short* src = WhTp3 + ((size_t)(ccbase + (c)) * 512 + wave * 64 + lane) * 8; \
        __builtin_amdgcn_global_load_lds(src, &bbuf[b][wave * 512], 16, 0, 0);          \
    }

    STAGE(0, 0);
    STAGE(1, 1);

    #pragma unroll
    for (int c = 0; c < NCHUNK; ++c) {
        const int par = c % 3;

        __builtin_amdgcn_sched_barrier(0);
        if (c < NCHUNK - 1) {
            asm volatile("s_waitcnt vmcnt(1)" ::: "memory");   // DMA(c) landed; DMA(c+1) in flight
        } else {
            asm volatile("s_waitcnt vmcnt(0)" ::: "memory");   // final chunk
        }
        __builtin_amdgcn_s_barrier();                           // all waves' DMA(c) landed
        __builtin_amdgcn_sched_barrier(0);

        if (c + 2 < NCHUNK) STAGE(c + 2, (c + 2) % 3);          // buf read last in iter c-1
        __builtin_amdgcn_sched_barrier(0);

        // bits from LDS (broadcast within g-groups)
        const int ql  = c >> 2;
        const int sub = c & 3;
        const int sh  = sub * 16 + g;
        const ulonglong2 Wd01 = *(const ulonglong2*)&bitlds[wave][ql][i16][0];
        const ulonglong2 Wd23 = *(const ulonglong2*)&bitlds[wave][ql][i16][2];
        const unsigned u0 = (unsigned)(Wd01.x >> sh);
        const unsigned u1 = (unsigned)(Wd01.y >> sh);
        const unsigned u2 = (unsigned)(Wd23.x >> sh);
        const unsigned u3 = (unsigned)(Wd23.y >> sh);

        // Wh2 from LDS (broadcast)
        const float* wp = &wh2lds[c * 64 + g * 4];
        const float4 W0 = *(const float4*)(wp);
        const float4 W1 = *(const float4*)(wp + 16);
        const float4 W2 = *(const float4*)(wp + 32);
        const float4 W3 = *(const float4*)(wp + 48);

        // B frags from LDS: lane base L*128 bytes, slot (2q+h)^(L&7)
        const unsigned short* lb = &bbuf[par][lane * 64];
        const bf16x8 B00 = *(const bf16x8*)(lb + ((0 ^ (lane & 7)) * 8));
        const bf16x8 B01 = *(const bf16x8*)(lb + ((1 ^ (lane & 7)) * 8));
        const bf16x8 B10 = *(const bf16x8*)(lb + ((2 ^ (lane & 7)) * 8));
        const bf16x8 B11 = *(const bf16x8*)(lb + ((3 ^ (lane & 7)) * 8));
        const bf16x8 B20 = *(const bf16x8*)(lb + ((4 ^ (lane & 7)) * 8));
        const bf16x8 B21 = *(const bf16x8*)(lb + ((5 ^ (lane & 7)) * 8));
        const bf16x8 B30 = *(const bf16x8*)(lb + ((6 ^ (lane & 7)) * 8));
        const bf16x8 B31 = *(const bf16x8*)(lb + ((7 ^ (lane & 7)) * 8));

        // element (m, d): col = cc*64 + m*16 + g*4 + d; gate = bit 4m of u_d
        bf16x8 af0, af1;
        af0[0] = (short)f2bf(pb(u0,  0, W0.x, wh1v, lsum));
        af0[1] = (short)f2bf(pb(u1,  0, W0.y, wh1v, lsum));
        af0[2] = (short)f2bf(pb(u2,  0, W0.z, wh1v, lsum));
        af0[3] = (short)f2bf(pb(u3,  0, W0.w, wh1v, lsum));
        af0[4] = (short)f2bf(pb(u0,  4, W1.x, wh1v, lsum));
        af0[5] = (short)f2bf(pb(u1,  4, W1.y, wh1v, lsum));
        af0[6] = (short)f2bf(pb(u2,  4, W1.z, wh1v, lsum));
        af0[7] = (short)f2bf(pb(u3,  4, W1.w, wh1v, lsum));
        af1[0] = (short)f2bf(pb(u0,  8, W2.x, wh1v, lsum));
        af1[1] = (short)f2bf(pb(u1,  8, W2.y, wh1v, lsum));
        af1[2] = (short)f2bf(pb(u2,  8, W2.z, wh1v, lsum));
        af1[3] = (short)f2bf(pb(u3,  8, W2.w, wh1v, lsum));
        af1[4] = (short)f2bf(pb(u0, 12, W3.x, wh1v, lsum));
        af1[5] = (short)f2bf(pb(u1, 12, W3.y, wh1v, lsum));
        af1[6] = (short)f2bf(pb(u2, 12, W3.z, wh1v, lsum));
        af1[7] = (short)f2bf(pb(u3, 12, W3.w, wh1v, lsum));

        acc0 = __builtin_amdgcn_mfma_f32_16x16x32_bf16(af0, B00, acc0, 0, 0, 0);
        acc1 = __builtin_amdgcn_mfma_f32_16x16x32_bf16(af0, B10, acc1, 0, 0, 0);
        acc2 = __builtin_amdgcn_mfma_f32_16x16x32_bf16(af0, B20, acc2, 0, 0, 0);
        acc3 = __builtin_amdgcn_mfma_f32_16x16x32_bf16(af0, B30, acc3, 0, 0, 0);
        acc0 = __builtin_amdgcn_mfma_f32_16x16x32_bf16(af1, B01, acc0, 0, 0, 0);
        acc1 = __builtin_amdgcn_mfma_f32_16x16x32_bf16(af1, B11, acc1, 0, 0, 0);
        acc2 = __builtin_amdgcn_mfma_f32_16x16x32_bf16(af1, B21, acc2, 0, 0, 0);
        acc3 = __builtin_amdgcn_mfma_f32_16x16x32_bf16(af1, B31, acc3, 0, 0, 0);
    }
#undef STAGE

    // per-row lsum: combine the 4 g-subgroups (xor 16/32 varies g only)
    lsum += __shfl_xor(lsum, 16);
    lsum += __shfl_xor(lsum, 32);

    // D layout (m89): row = g*4 + r (wave-private rows -> direct partial writes)
    #pragma unroll
    for (int r = 0; r < 4; ++r) {
        const int row = Rw + g * 4 + r;
        float* pr = pacc + ((size_t)slice * N_NODES + row) * D_OUT + i16;
        pr[ 0] = acc0[r];
        pr[16] = acc1[r];
        pr[32] = acc2[r];
        pr[48] = acc3[r];
    }
    if (lane < 16) plsum[(size_t)slice * N_NODES + Rw + lane] = lsum;
}

// ---------------- Kernel C: sum KSPLIT partials, normalize, ELU ----------------
__global__ __launch_bounds__(256) void k_finish(const float* __restrict__ pacc,
                                                const float* __restrict__ plsum,
                                                float* __restrict__ out) {
    const int idx = blockIdx.x * 256 + threadIdx.x;
    const int row = idx >> 4;
    const int tf4 = (idx & 15) * 4;
    float4 s = {0.f, 0.f, 0.f, 0.f};
    float L = 0.f;
    #pragma unroll
    for (int k = 0; k < KSPLIT; ++k) {
        float4 v = *(const float4*)&pacc[((size_t)k * N_NODES + row) * D_OUT + tf4];
        s.x += v.x; s.y += v.y; s.z += v.z; s.w += v.w;
        L += plsum[(size_t)k * N_NODES + row];
    }
    const float inv = (L > 0.f) ? 1.f / L : 0.f;
    float4 o;
    o.x = s.x * inv; o.y = s.y * inv; o.z = s.z * inv; o.w = s.w * inv;
    o.x = (o.x > 0.f) ? o.x : (__expf(o.x) - 1.f);
    o.y = (o.y > 0.f) ? o.y : (__expf(o.y) - 1.f);
    o.z = (o.z > 0.f) ? o.z : (__expf(o.z) - 1.f);
    o.w = (o.w > 0.f) ? o.w : (__expf(o.w) - 1.f);
    *(float4*)&out[(size_t)row * D_OUT + tf4] = o;
}

extern "C" void kernel_launch(void* const* d_in, const int* in_sizes, int n_in,
                              void* d_out, int out_size, void* d_ws, size_t ws_size,
                              hipStream_t stream) {
    const float* h    = (const float*)d_in[0];
    const float* mask = (const float*)d_in[1];
    // d_in[2] = lamda: unused (dischange==0 makes the mask-update a no-op)
    const float* W    = (const float*)d_in[3];
    const float* a    = (const float*)d_in[4];
    float* out = (float*)d_out;

    // ws: WhTp3 1MB | Wh1 32KB | Wh2 32KB | bits 8MB | pacc 16MB | plsum 256KB
    unsigned short* WhTp3 = (unsigned short*)d_ws;
    float* Wh1 = (float*)((char*)d_ws + (size_t)D_OUT * N_NODES * sizeof(unsigned short));
    float* Wh2 = Wh1 + N_NODES;
    unsigned long long* bitsw = (unsigned long long*)(Wh2 + N_NODES);
    float* pacc = (float*)(bitsw + (size_t)N_NODES * (N_NODES / 64));
    float* plsum = pacc + (size_t)KSPLIT * N_NODES * D_OUT;

    k_front<<<GEMM_BLOCKS + N_NODES / 4, 256, 0, stream>>>(h, W, a, mask, WhTp3, Wh1, Wh2, bitsw);
    k_attn<<<(N_NODES / 128) * KSPLIT, 512, 0, stream>>>(bitsw, WhTp3, Wh1, Wh2, pacc, plsum);
    k_finish<<<(N_NODES * D_OUT / 4) / 256, 256, 0, stream>>>(pacc, plsum, out);
}

// Round 22
// 86.260 us; speedup vs baseline: 1.7902x; 1.2260x over previous
//
#include <hip/hip_runtime.h>

#define N_NODES 8192
#define D_IN 512
#define D_OUT 64
#define LRELU_ALPHA 0.2f
#define KSPLIT 8
#define KSLICE (N_NODES / KSPLIT)    // 1024 cols per fused block
#define NCHUNK (KSLICE / 64)         // 16 chunks of 64 cols

typedef __attribute__((ext_vector_type(8))) short bf16x8;
typedef __attribute__((ext_vector_type(4))) float f32x4;

__device__ __forceinline__ unsigned short f2bf(float x) {
    unsigned u = __float_as_uint(x);
    u += 0x7fffu + ((u >> 16) & 1u);   // round-to-nearest-even
    return (unsigned short)(u >> 16);
}

// mask-gated p: e = lrelu(wh1+w2); p = mk * exp(e)  (mask is exactly 0.0/1.0)
__device__ __forceinline__ float pgate(float mk, float w2v, float wh1v, float& lsum) {
    float e = wh1v + w2v;
    e = fmaxf(e, LRELU_ALPHA * e);
    float p = mk * __expf(e);
    lsum += p;
    return p;
}

// ---------------- Kernel 1: pure gemm; epilogue writes WhTp3 (R18 layout), Wh1, Wh2 ----------------
__global__ __launch_bounds__(256) void k_gemm(const float* __restrict__ h,
                                              const float* __restrict__ W,
                                              const float* __restrict__ a,
                                              unsigned short* __restrict__ WhTp3,
                                              float* __restrict__ Wh1,
                                              float* __restrict__ Wh2) {
    __shared__ float hs[32][68];
    __shared__ float Ws[64][64];
    const int tid = threadIdx.x;
    const int r0 = blockIdx.x * 32;
    const int tf = tid & 15;
    const int tr = tid >> 4;
    float acc[2][4] = {{0.f,0.f,0.f,0.f},{0.f,0.f,0.f,0.f}};

    for (int kc = 0; kc < D_IN; kc += 64) {
        {
            int rr = tid >> 4;
            int cc = (tid & 15) * 4;
            float4 v0 = *(const float4*)&h[(size_t)(r0 + rr) * D_IN + kc + cc];
            float4 v1 = *(const float4*)&h[(size_t)(r0 + rr + 16) * D_IN + kc + cc];
            *(float4*)&hs[rr][cc] = v0;
            *(float4*)&hs[rr + 16][cc] = v1;
        }
        #pragma unroll
        for (int p = 0; p < 4; ++p) {
            int kk = (tid >> 4) + p * 16;
            int cc = (tid & 15) * 4;
            *(float4*)&Ws[kk][cc] = *(const float4*)&W[(size_t)(kc + kk) * D_OUT + cc];
        }
        __syncthreads();
        #pragma unroll
        for (int k = 0; k < 64; k += 4) {
            float4 a0 = *(const float4*)&hs[tr*2][k];
            float4 a1 = *(const float4*)&hs[tr*2+1][k];
            float av0[4] = {a0.x, a0.y, a0.z, a0.w};
            float av1[4] = {a1.x, a1.y, a1.z, a1.w};
            #pragma unroll
            for (int kk = 0; kk < 4; ++kk) {
                float4 b = *(const float4*)&Ws[k+kk][tf*4];
                acc[0][0] += av0[kk]*b.x; acc[0][1] += av0[kk]*b.y;
                acc[0][2] += av0[kk]*b.z; acc[0][3] += av0[kk]*b.w;
                acc[1][0] += av1[kk]*b.x; acc[1][1] += av1[kk]*b.y;
                acc[1][2] += av1[kk]*b.z; acc[1][3] += av1[kk]*b.w;
            }
        }
        __syncthreads();
    }
    const int orow = r0 + tr*2;   // even

    // WhTp3 epilogue (R18 layout): [cc][L][slot s][j], s = (2q+h)^(L&7)
    {
        const int cc  = orow >> 6;
        const int cw  = orow & 63;
        const int hh  = cw >> 5;
        const int rem = cw & 31;
        const int jhi = rem >> 4;
        const int gg  = (rem >> 2) & 3;
        const int jlo = cw & 3;          // even
        const int j   = jhi * 4 + jlo;
        #pragma unroll
        for (int k = 0; k < 4; ++k) {
            const int f = tf * 4 + k;
            const int L = gg * 16 + (f & 15);
            const int s = (2 * (f >> 4) + hh) ^ (L & 7);
            const size_t sidx = ((size_t)(cc * 64 + L) * 8 + s) * 8 + j;
            unsigned v = (unsigned)f2bf(acc[0][k]) | ((unsigned)f2bf(acc[1][k]) << 16);
            *(unsigned*)&WhTp3[sidx] = v;
        }
    }

    float a1v[4], a2v[4];
    #pragma unroll
    for (int k = 0; k < 4; ++k) { a1v[k] = a[tf*4 + k]; a2v[k] = a[64 + tf*4 + k]; }
    float s1 = 0.f, t1 = 0.f, s2 = 0.f, t2 = 0.f;
    #pragma unroll
    for (int k = 0; k < 4; ++k) {
        s1 += acc[0][k] * a1v[k];
        t1 += acc[1][k] * a1v[k];
        s2 += acc[0][k] * a2v[k];
        t2 += acc[1][k] * a2v[k];
    }
    #pragma unroll
    for (int d = 1; d < 16; d <<= 1) {
        s1 += __shfl_xor(s1, d);
        t1 += __shfl_xor(t1, d);
        s2 += __shfl_xor(s2, d);
        t2 += __shfl_xor(t2, d);
    }
    if (tf == 0) {
        Wh1[orow] = s1; Wh1[orow + 1] = t1;
        Wh2[orow] = s2; Wh2[orow + 1] = t2;
    }
}

// ---------------- Kernel 2: FUSED mask-stream + block-staged-B masked-softmax/PV ----------------
// R18's attn structure (512 blocks = 64 rowgroups x 8 slices, 8 waves row-split, 8KB
// B-window staged per chunk via 1KB-contiguous global_load_lds/wave) with the bits
// intermediate DELETED: each lane reads its 4 mask float4s directly from HBM and gates
// with mk*exp(e) (R12's verified form). The mask stream (previously a separate serial
// ~50us kernel) now overlaps the MFMA/VALU compute (previously a separate serial ~40us
// kernel). Each mask element read exactly once. Wh2 hoisted to LDS in the prologue.
__global__ __launch_bounds__(512, 4) void k_fused(const float* __restrict__ mask,
                                                  const unsigned short* __restrict__ WhTp3,
                                                  const float* __restrict__ Wh1,
                                                  const float* __restrict__ Wh2,
                                                  float* __restrict__ pacc,
                                                  float* __restrict__ plsum) {
    __shared__ unsigned short bbuf[2][4096];   // 16 KB: B-window double buffer
    __shared__ float wh2lds[KSLICE];           // 4 KB: slice's Wh2

    const int tid  = threadIdx.x;
    const int wave = tid >> 6;       // 0..7: strip within rowgroup
    const int lane = tid & 63;
    const int i16 = lane & 15;
    const int g   = lane >> 4;
    const int rg    = blockIdx.x >> 3;
    const int slice = blockIdx.x & 7;
    const int Rw    = rg * 128 + wave * 16;     // this wave's 16 rows
    const int ccbase = slice * NCHUNK;          // first 64-col window

    const float wh1v = Wh1[Rw + i16];
    const float* mrow = mask + (size_t)(Rw + i16) * N_NODES + slice * KSLICE;

    // prologue: hoist Wh2 slice to LDS
    if (tid < 256) {
        *(float4*)&wh2lds[tid * 4] = *(const float4*)&Wh2[ccbase * 64 + tid * 4];
    }

    f32x4 acc0 = {0.f,0.f,0.f,0.f}, acc1 = {0.f,0.f,0.f,0.f};
    f32x4 acc2 = {0.f,0.f,0.f,0.f}, acc3 = {0.f,0.f,0.f,0.f};
    float lsum = 0.f;

    // stage chunk c's 8KB B-window: one contiguous 1KB DMA per wave (linear dest, m104)
#define STAGE(c, par)                                                                   \
    {                                                                                   \
        const unsigned short* src = WhTp3 + ((size_t)(ccbase + (c)) * 512 + wave * 64 + lane) * 8; \
        __builtin_amdgcn_global_load_lds(src, &bbuf[par][wave * 512], 16, 0, 0);        \
    }

    STAGE(0, 0);
    __syncthreads();   // also covers wh2lds

    #pragma unroll 2
    for (int c = 0; c < NCHUNK; ++c) {
        const int par = c & 1;

        // ---- mask loads (the BW stream): 4 float4 per lane, each element read once ----
        const float* mp = mrow + c * 64 + g * 4;
        const float4 M0 = *(const float4*)(mp);
        const float4 M1 = *(const float4*)(mp + 16);
        const float4 M2 = *(const float4*)(mp + 32);
        const float4 M3 = *(const float4*)(mp + 48);

        // ---- next B-window DMA (youngest vmem) ----
        if (c + 1 < NCHUNK) STAGE(c + 1, par ^ 1);
        __builtin_amdgcn_sched_barrier(0);

        // Wh2 from LDS (broadcast)
        const float* wp = &wh2lds[c * 64 + g * 4];
        const float4 W0 = *(const float4*)(wp);
        const float4 W1 = *(const float4*)(wp + 16);
        const float4 W2 = *(const float4*)(wp + 32);
        const float4 W3 = *(const float4*)(wp + 48);

        // B frags from LDS: lane base L*128 bytes, slot (2q+h)^(L&7)
        const unsigned short* lb = &bbuf[par][lane * 64];
        const bf16x8 B00 = *(const bf16x8*)(lb + ((0 ^ (lane & 7)) * 8));
        const bf16x8 B01 = *(const bf16x8*)(lb + ((1 ^ (lane & 7)) * 8));
        const bf16x8 B10 = *(const bf16x8*)(lb + ((2 ^ (lane & 7)) * 8));
        const bf16x8 B11 = *(const bf16x8*)(lb + ((3 ^ (lane & 7)) * 8));
        const bf16x8 B20 = *(const bf16x8*)(lb + ((4 ^ (lane & 7)) * 8));
        const bf16x8 B21 = *(const bf16x8*)(lb + ((5 ^ (lane & 7)) * 8));
        const bf16x8 B30 = *(const bf16x8*)(lb + ((6 ^ (lane & 7)) * 8));
        const bf16x8 B31 = *(const bf16x8*)(lb + ((7 ^ (lane & 7)) * 8));

        // element (m, d): col = cc*64 + m*16 + g*4 + d  <->  M_m component d
        bf16x8 af0, af1;
        af0[0] = (short)f2bf(pgate(M0.x, W0.x, wh1v, lsum));
        af0[1] = (short)f2bf(pgate(M0.y, W0.y, wh1v, lsum));
        af0[2] = (short)f2bf(pgate(M0.z, W0.z, wh1v, lsum));
        af0[3] = (short)f2bf(pgate(M0.w, W0.w, wh1v, lsum));
        af0[4] = (short)f2bf(pgate(M1.x, W1.x, wh1v, lsum));
        af0[5] = (short)f2bf(pgate(M1.y, W1.y, wh1v, lsum));
        af0[6] = (short)f2bf(pgate(M1.z, W1.z, wh1v, lsum));
        af0[7] = (short)f2bf(pgate(M1.w, W1.w, wh1v, lsum));
        af1[0] = (short)f2bf(pgate(M2.x, W2.x, wh1v, lsum));
        af1[1] = (short)f2bf(pgate(M2.y, W2.y, wh1v, lsum));
        af1[2] = (short)f2bf(pgate(M2.z, W2.z, wh1v, lsum));
        af1[3] = (short)f2bf(pgate(M2.w, W2.w, wh1v, lsum));
        af1[4] = (short)f2bf(pgate(M3.x, W3.x, wh1v, lsum));
        af1[5] = (short)f2bf(pgate(M3.y, W3.y, wh1v, lsum));
        af1[6] = (short)f2bf(pgate(M3.z, W3.z, wh1v, lsum));
        af1[7] = (short)f2bf(pgate(M3.w, W3.w, wh1v, lsum));

        acc0 = __builtin_amdgcn_mfma_f32_16x16x32_bf16(af0, B00, acc0, 0, 0, 0);
        acc1 = __builtin_amdgcn_mfma_f32_16x16x32_bf16(af0, B10, acc1, 0, 0, 0);
        acc2 = __builtin_amdgcn_mfma_f32_16x16x32_bf16(af0, B20, acc2, 0, 0, 0);
        acc3 = __builtin_amdgcn_mfma_f32_16x16x32_bf16(af0, B30, acc3, 0, 0, 0);
        acc0 = __builtin_amdgcn_mfma_f32_16x16x32_bf16(af1, B01, acc0, 0, 0, 0);
        acc1 = __builtin_amdgcn_mfma_f32_16x16x32_bf16(af1, B11, acc1, 0, 0, 0);
        acc2 = __builtin_amdgcn_mfma_f32_16x16x32_bf16(af1, B21, acc2, 0, 0, 0);
        acc3 = __builtin_amdgcn_mfma_f32_16x16x32_bf16(af1, B31, acc3, 0, 0, 0);

        if (c + 1 < NCHUNK) __syncthreads();   // STAGE(c+1) drained; bbuf[par] free
    }
#undef STAGE

    // per-row lsum: combine the 4 g-subgroups (xor 16/32 varies g only)
    lsum += __shfl_xor(lsum, 16);
    lsum += __shfl_xor(lsum, 32);

    // D layout (m89): row = g*4 + r (wave-private rows -> direct partial writes)
    #pragma unroll
    for (int r = 0; r < 4; ++r) {
        const int row = Rw + g * 4 + r;
        float* pr = pacc + ((size_t)slice * N_NODES + row) * D_OUT + i16;
        pr[ 0] = acc0[r];
        pr[16] = acc1[r];
        pr[32] = acc2[r];
        pr[48] = acc3[r];
    }
    if (lane < 16) plsum[(size_t)slice * N_NODES + Rw + lane] = lsum;
}

// ---------------- Kernel 3: sum KSPLIT partials, normalize, ELU ----------------
__global__ __launch_bounds__(256) void k_finish(const float* __restrict__ pacc,
                                                const float* __restrict__ plsum,
                                                float* __restrict__ out) {
    const int idx = blockIdx.x * 256 + threadIdx.x;
    const int row = idx >> 4;
    const int tf4 = (idx & 15) * 4;
    float4 s = {0.f, 0.f, 0.f, 0.f};
    float L = 0.f;
    #pragma unroll
    for (int k = 0; k < KSPLIT; ++k) {
        float4 v = *(const float4*)&pacc[((size_t)k * N_NODES + row) * D_OUT + tf4];
        s.x += v.x; s.y += v.y; s.z += v.z; s.w += v.w;
        L += plsum[(size_t)k * N_NODES + row];
    }
    const float inv = (L > 0.f) ? 1.f / L : 0.f;
    float4 o;
    o.x = s.x * inv; o.y = s.y * inv; o.z = s.z * inv; o.w = s.w * inv;
    o.x = (o.x > 0.f) ? o.x : (__expf(o.x) - 1.f);
    o.y = (o.y > 0.f) ? o.y : (__expf(o.y) - 1.f);
    o.z = (o.z > 0.f) ? o.z : (__expf(o.z) - 1.f);
    o.w = (o.w > 0.f) ? o.w : (__expf(o.w) - 1.f);
    *(float4*)&out[(size_t)row * D_OUT + tf4] = o;
}

extern "C" void kernel_launch(void* const* d_in, const int* in_sizes, int n_in,
                              void* d_out, int out_size, void* d_ws, size_t ws_size,
                              hipStream_t stream) {
    const float* h    = (const float*)d_in[0];
    const float* mask = (const float*)d_in[1];
    // d_in[2] = lamda: unused (dischange==0 makes the mask-update a no-op)
    const float* W    = (const float*)d_in[3];
    const float* a    = (const float*)d_in[4];
    float* out = (float*)d_out;

    // ws: WhTp3 1MB | Wh1 32KB | Wh2 32KB | pacc 16MB | plsum 256KB
    unsigned short* WhTp3 = (unsigned short*)d_ws;
    float* Wh1 = (float*)((char*)d_ws + (size_t)D_OUT * N_NODES * sizeof(unsigned short));
    float* Wh2 = Wh1 + N_NODES;
    float* pacc = Wh2 + N_NODES;
    float* plsum = pacc + (size_t)KSPLIT * N_NODES * D_OUT;

    k_gemm<<<N_NODES / 32, 256, 0, stream>>>(h, W, a, WhTp3, Wh1, Wh2);
    k_fused<<<(N_NODES / 128) * KSPLIT, 512, 0, stream>>>(mask, WhTp3, Wh1, Wh2, pacc, plsum);
    k_finish<<<(N_NODES * D_OUT / 4) / 256, 256, 0, stream>>>(pacc, plsum, out);
}